// Round 11
// baseline (165.204 us; speedup 1.0000x reference)
//
#include <hip/hip_runtime.h>
#include <hip/hip_bf16.h>

// LoRA-DoRA fused linear for MI355X (gfx950).
// Shapes: x[256][4096] f32, W[11008][4096] f32, A[64][4096], B[11008][64],
//         M[1][4096], bias[11008]; out[256][11008] f32.
// R11 = R10 with K2b batch-offset bugfix (y[(b0+b)] not y[b]).
// Structure: NO Wc materialization.  out = xs@W^T + y@B^T,
//   y = 2*(xs@A^T)  [256][64], norms from (W+2BA) computed in K1 (read-only).
//  K1': stream W (cacheable -> stays in L3 for K3'), MFMA lora tile, column
//       sum-of-squares of (W+2L) -> part_ss.  PURE READ (180 MB, no 90MB write).
//  K2 : scale = M/(sqrt(sum part_ss)+eps); xs = bf16(x*scale); blk(0,0) zeroes y.
//  K2b: y += 2*xs@A^T via LDS-staged VALU + f32 atomics.
//  K3': partK[kz] = xs @ bf16(W)^T.  256x128 tile, KSPLIT=4, W reg-staged
//       f32->bf16 (cvt_pk) with swizzled ds_write; kz==0 adds y@B^T as one
//       extra MFMA unit.  bf16 partials (R7/R9-verified neutral).
//  K4 : out = sum_kz bf2f(partK[kz]) + bias.

typedef __attribute__((ext_vector_type(8))) short bf16x8;
typedef __attribute__((ext_vector_type(4))) float f32x4;
typedef __attribute__((ext_vector_type(16))) float f32x16;
typedef __attribute__((ext_vector_type(4))) unsigned short u16x4;
typedef __attribute__((ext_vector_type(8))) unsigned short u16x8;

#define OUT_DIM 11008
#define IN_DIM  4096
#define M_DIM   256
#define KSPLIT  4
#define NBLK_O  86   // OUT_DIM / 128

static __device__ __forceinline__ unsigned short f2bf(float f) {
  union { float f; unsigned u; } v; v.f = f;
  unsigned r = (v.u + 0x7fffu + ((v.u >> 16) & 1u)) >> 16;  // RNE
  return (unsigned short)r;
}
static __device__ __forceinline__ float bf2f(unsigned short h) {
  union { unsigned u; float f; } v; v.u = ((unsigned)h) << 16;
  return v.f;
}
// Pack 8 f32 -> 8 bf16 (RNE); element j of result = input j.
static __device__ __forceinline__ u16x8 pack8(const f32x4 a, const f32x4 b) {
  union { unsigned w[4]; u16x8 v; } u;
  __hip_bfloat162 t;
  t = __float22bfloat162_rn(make_float2(a[0], a[1])); u.w[0] = *reinterpret_cast<unsigned*>(&t);
  t = __float22bfloat162_rn(make_float2(a[2], a[3])); u.w[1] = *reinterpret_cast<unsigned*>(&t);
  t = __float22bfloat162_rn(make_float2(b[0], b[1])); u.w[2] = *reinterpret_cast<unsigned*>(&t);
  t = __float22bfloat162_rn(make_float2(b[2], b[3])); u.w[3] = *reinterpret_cast<unsigned*>(&t);
  return u.v;
}

#define GLOAD_LDS16(gptr, lptr)                                                        \
  __builtin_amdgcn_global_load_lds(                                                    \
      (const __attribute__((address_space(1))) unsigned int*)(gptr),                   \
      (__attribute__((address_space(3))) unsigned int*)(lptr), 16, 0, 0)

// ---------------------------------------------------------------------------
// K1': norms only (no Wc write).  grid (32, 86), block 256.
// ---------------------------------------------------------------------------
__global__ __launch_bounds__(256) void k1_norm(
    const float* __restrict__ W,
    const float* __restrict__ lA,   // [64][4096]
    const float* __restrict__ lB,   // [11008][64]
    float* __restrict__ part_ss)    // [86][4096]
{
  const int i0 = blockIdx.x * 128;
  const int o0 = blockIdx.y * 128;
  const int tid = threadIdx.x;
  const int lane = tid & 63;
  const int wid = tid >> 6;
  const int wr = wid >> 1, wc = wid & 1;

  __shared__ unsigned short smem[2][128][72];
  for (int idx = tid; idx < 64 * 128; idx += 256) {
    const int r = idx >> 7, c = idx & 127;
    smem[0][c][r] = f2bf(lA[r * IN_DIM + i0 + c]);
  }
  for (int idx = tid; idx < 128 * 64; idx += 256) {
    const int o = idx >> 6, r = idx & 63;
    smem[1][o][r] = f2bf(lB[(o0 + o) * 64 + r]);
  }
  __syncthreads();

  f32x4 acc[4][4];
  #pragma unroll
  for (int a = 0; a < 4; ++a)
    #pragma unroll
    for (int b = 0; b < 4; ++b) acc[a][b] = (f32x4){0.f, 0.f, 0.f, 0.f};

  #pragma unroll
  for (int kk = 0; kk < 2; ++kk) {
    const int kofs = kk * 32 + (lane >> 4) * 8;
    bf16x8 af[4], bfr[4];
    #pragma unroll
    for (int mi = 0; mi < 4; ++mi)
      af[mi] = *reinterpret_cast<const bf16x8*>(&smem[1][wr * 64 + mi * 16 + (lane & 15)][kofs]);
    #pragma unroll
    for (int ni = 0; ni < 4; ++ni)
      bfr[ni] = *reinterpret_cast<const bf16x8*>(&smem[0][wc * 64 + ni * 16 + (lane & 15)][kofs]);
    #pragma unroll
    for (int mi = 0; mi < 4; ++mi)
      #pragma unroll
      for (int ni = 0; ni < 4; ++ni)
        acc[mi][ni] = __builtin_amdgcn_mfma_f32_16x16x32_bf16(af[mi], bfr[ni], acc[mi][ni], 0, 0, 0);
  }
  __syncthreads();

  unsigned short* L = &smem[0][0][0];
  #pragma unroll
  for (int mi = 0; mi < 4; ++mi) {
    const int ol = wr * 64 + mi * 16 + (lane >> 4) * 4;
    #pragma unroll
    for (int ni = 0; ni < 4; ++ni) {
      const int il = wc * 64 + ni * 16 + (lane & 15);
      #pragma unroll
      for (int j = 0; j < 4; ++j)
        L[(ol + j) * 136 + il] = f2bf(acc[mi][ni][j]);
    }
  }
  __syncthreads();

  // Streaming phase: CACHEABLE f32x4 reads of W (we want W in L3 for K3').
  const int c4 = (tid & 31) * 4;
  const int r0 = tid >> 5;
  float sq0 = 0.f, sq1 = 0.f, sq2 = 0.f, sq3 = 0.f;
  #pragma unroll
  for (int it = 0; it < 16; ++it) {
    const int rr = r0 + it * 8;
    const size_t go = (size_t)(o0 + rr) * IN_DIM + i0 + c4;
    const f32x4 w = *reinterpret_cast<const f32x4*>(&W[go]);
    const u16x4 lv = *reinterpret_cast<const u16x4*>(&L[rr * 136 + c4]);
    const float w0 = w[0] + 2.f * bf2f(lv[0]);
    const float w1 = w[1] + 2.f * bf2f(lv[1]);
    const float w2 = w[2] + 2.f * bf2f(lv[2]);
    const float w3 = w[3] + 2.f * bf2f(lv[3]);
    sq0 += w0 * w0; sq1 += w1 * w1; sq2 += w2 * w2; sq3 += w3 * w3;
  }
  __syncthreads();
  float* red = reinterpret_cast<float*>(L);
  red[((r0 << 5) | (tid & 31)) * 4 + 0] = sq0;
  red[((r0 << 5) | (tid & 31)) * 4 + 1] = sq1;
  red[((r0 << 5) | (tid & 31)) * 4 + 2] = sq2;
  red[((r0 << 5) | (tid & 31)) * 4 + 3] = sq3;
  __syncthreads();
  if (tid < 128) {
    const int cc = tid >> 2, k = tid & 3;
    float s = 0.f;
    #pragma unroll
    for (int g = 0; g < 8; ++g) s += red[(((g << 5) | cc) << 2) + k];
    part_ss[(size_t)blockIdx.y * IN_DIM + i0 + tid] = s;
  }
}

// ---------------------------------------------------------------------------
// K2: fused scale + xs; block(0,0) zeroes y.  grid (16, 16), block 256.
// ---------------------------------------------------------------------------
__global__ __launch_bounds__(256) void k2_xs(
    const float* __restrict__ x, const float* __restrict__ lM,
    const float* __restrict__ part_ss, unsigned short* __restrict__ xs,
    float* __restrict__ y)
{
  const int i = blockIdx.x * 256 + threadIdx.x;
  const int b0 = blockIdx.y * 16;
  float s = 0.f;
  #pragma unroll 2
  for (int b = 0; b < NBLK_O; ++b) s += part_ss[(size_t)b * IN_DIM + i];
  const float sc = lM[i] / (sqrtf(s) + 1e-6f);
  #pragma unroll 4
  for (int r = 0; r < 16; ++r) {
    const size_t o = (size_t)(b0 + r) * IN_DIM + i;
    xs[o] = f2bf(x[o] * sc);
  }
  if (blockIdx.x == 0 && blockIdx.y == 0) {
    f32x4* yz = reinterpret_cast<f32x4*>(y);
    const f32x4 z = {0.f, 0.f, 0.f, 0.f};
    #pragma unroll
    for (int j = 0; j < 16; ++j) yz[threadIdx.x * 16 + j] = z;  // 16384 f32
  }
}

// ---------------------------------------------------------------------------
// K2b: y[b0+b][r] += 2*sum_i xs[b0+b,i]*A[r,i].  grid (32 ichunks, 4 bgrp), 256.
// ---------------------------------------------------------------------------
__global__ __launch_bounds__(256) void k2b_y(
    const unsigned short* __restrict__ xs,  // [256][4096] bf16
    const float* __restrict__ lA,           // [64][4096]
    float* __restrict__ y)                  // [256][64] f32 (pre-zeroed by K2)
{
  __shared__ unsigned short xsl[64 * 132];
  __shared__ float Al[64 * 128];
  const int i0 = blockIdx.x * 128;
  const int b0 = blockIdx.y * 64;
  const int tid = threadIdx.x;
  {
    const int r = tid >> 2, q = tid & 3;  // 4 thr/row
    const unsigned short* src = &xs[(size_t)(b0 + r) * IN_DIM + i0 + q * 32];
    #pragma unroll
    for (int j = 0; j < 8; ++j)
      *reinterpret_cast<u16x4*>(&xsl[r * 132 + q * 32 + j * 4]) =
          *reinterpret_cast<const u16x4*>(&src[j * 4]);
    const float* asrc = &lA[(size_t)r * IN_DIM + i0 + q * 32];
    #pragma unroll
    for (int j = 0; j < 8; ++j)
      *reinterpret_cast<f32x4*>(&Al[r * 128 + q * 32 + j * 4]) =
          *reinterpret_cast<const f32x4*>(&asrc[j * 4]);
  }
  __syncthreads();
  const int b = tid & 63, rq = tid >> 6;
  float acc[16];
  #pragma unroll
  for (int rr = 0; rr < 16; ++rr) acc[rr] = 0.f;
  for (int i = 0; i < 128; ++i) {
    const float xv = bf2f(xsl[b * 132 + i]);
    #pragma unroll
    for (int rr = 0; rr < 16; ++rr)
      acc[rr] += xv * Al[(rq * 16 + rr) * 128 + i];  // broadcast read
  }
  #pragma unroll
  for (int rr = 0; rr < 16; ++rr)
    atomicAdd(&y[(b0 + b) * 64 + rq * 16 + rr], 2.f * acc[rr]);  // R11 FIX: +b0
}

// ---------------------------------------------------------------------------
// K3': partK[kz] = xs @ bf16(W)^T (+ y@B^T on kz==0).  grid (86,4), block 512.
// 256x128 tile; As = xs via gload_lds (pre-swizzled source); Bs = W f32
// reg-staged -> cvt_pk -> swizzled ds_write (both-sides swizzle).
// ---------------------------------------------------------------------------
__global__ __launch_bounds__(512) void k3_gemm(
    const unsigned short* __restrict__ xs,  // [256][4096] bf16
    const float* __restrict__ W,            // [11008][4096] f32 (L3-resident)
    const float* __restrict__ lB,           // [11008][64] f32
    const float* __restrict__ y,            // [256][64] f32
    unsigned short* __restrict__ partK)     // [KSPLIT][256][11008] bf16
{
  const int n0 = blockIdx.x * 128;
  const int kz = blockIdx.y;
  const int tid = threadIdx.x;
  const int lane = tid & 63;
  const int wid = tid >> 6;
  const int wm = wid >> 1, wn = wid & 1;

  __shared__ unsigned short As[256 * 64];   // 32 KB
  __shared__ unsigned short Bs[128 * 64];   // 16 KB

  f32x16 acc[2][2];
  #pragma unroll
  for (int a = 0; a < 2; ++a)
    #pragma unroll
    for (int b = 0; b < 2; ++b)
      #pragma unroll
      for (int r = 0; r < 16; ++r) acc[a][b][r] = 0.f;

  const int k0base = kz * (IN_DIM / KSPLIT);
  const int srow = tid >> 3;               // 0..63  (As staging)
  const int g    = tid & 7;
  const int gc   = (g ^ (srow & 7)) * 8;   // pre-swizzled source col
  const int ldstA = srow * 64 + g * 8;
  const int r2 = tid >> 2;                 // 0..127 (Bs staging)
  const int q2 = tid & 3;
  const int bs0 = r2 * 64 + (((q2 * 2)     ^ (r2 & 7)) * 8);
  const int bs1 = r2 * 64 + (((q2 * 2 + 1) ^ (r2 & 7)) * 8);

  for (int ks = 0; ks < (IN_DIM / KSPLIT) / 64; ++ks) {  // 16 steps
    const int k0 = k0base + ks * 64;
    #pragma unroll
    for (int iss = 0; iss < 4; ++iss)
      GLOAD_LDS16(&xs[(size_t)(srow + 64 * iss) * IN_DIM + k0 + gc],
                  &As[iss * 64 * 64 + ldstA]);
    {  // W f32 -> bf16 reg-stage
      const float* wp = &W[(size_t)(n0 + r2) * IN_DIM + k0 + q2 * 16];
      const f32x4 w0 = *reinterpret_cast<const f32x4*>(wp);
      const f32x4 w1 = *reinterpret_cast<const f32x4*>(wp + 4);
      *reinterpret_cast<u16x8*>(&Bs[bs0]) = pack8(w0, w1);
      const f32x4 w2 = *reinterpret_cast<const f32x4*>(wp + 8);
      const f32x4 w3 = *reinterpret_cast<const f32x4*>(wp + 12);
      *reinterpret_cast<u16x8*>(&Bs[bs1]) = pack8(w2, w3);
    }
    __syncthreads();
    #pragma unroll
    for (int kk = 0; kk < 4; ++kk) {
      const int kb = kk * 16 + (lane >> 5) * 8;
      bf16x8 af[2], bfr[2];
      #pragma unroll
      for (int mi = 0; mi < 2; ++mi) {
        const int Ra = wm * 64 + mi * 32 + (lane & 31);
        af[mi] = *reinterpret_cast<const bf16x8*>(&As[Ra * 64 + (kb ^ ((Ra & 7) << 3))]);
      }
      #pragma unroll
      for (int ni = 0; ni < 2; ++ni) {
        const int Rb = wn * 64 + ni * 32 + (lane & 31);
        bfr[ni] = *reinterpret_cast<const bf16x8*>(&Bs[Rb * 64 + (kb ^ ((Rb & 7) << 3))]);
      }
      #pragma unroll
      for (int mi = 0; mi < 2; ++mi)
        #pragma unroll
        for (int ni = 0; ni < 2; ++ni)
          acc[mi][ni] = __builtin_amdgcn_mfma_f32_32x32x16_bf16(af[mi], bfr[ni], acc[mi][ni], 0, 0, 0);
    }
    __syncthreads();
  }

  if (kz == 0) {  // rank-64 lora unit: acc += y @ B_tile^T
    {  // stage y [256][64] f32 -> As bf16 (swizzled writes)
      const int ry = tid >> 1, qy = tid & 1;
      const float* yp = &y[ry * 64 + qy * 32];
      #pragma unroll
      for (int j = 0; j < 4; ++j) {
        const f32x4 a = *reinterpret_cast<const f32x4*>(yp + j * 8);
        const f32x4 b = *reinterpret_cast<const f32x4*>(yp + j * 8 + 4);
        *reinterpret_cast<u16x8*>(&As[ry * 64 + (((qy * 4 + j) ^ (ry & 7)) * 8)]) = pack8(a, b);
      }
    }
    {  // stage B tile [128][64] f32 -> Bs (same path as W)
      const float* bp = &lB[(size_t)(n0 + r2) * 64 + q2 * 16];
      const f32x4 b0 = *reinterpret_cast<const f32x4*>(bp);
      const f32x4 b1 = *reinterpret_cast<const f32x4*>(bp + 4);
      *reinterpret_cast<u16x8*>(&Bs[bs0]) = pack8(b0, b1);
      const f32x4 b2 = *reinterpret_cast<const f32x4*>(bp + 8);
      const f32x4 b3 = *reinterpret_cast<const f32x4*>(bp + 12);
      *reinterpret_cast<u16x8*>(&Bs[bs1]) = pack8(b2, b3);
    }
    __syncthreads();
    #pragma unroll
    for (int kk = 0; kk < 4; ++kk) {
      const int kb = kk * 16 + (lane >> 5) * 8;
      bf16x8 af[2], bfr[2];
      #pragma unroll
      for (int mi = 0; mi < 2; ++mi) {
        const int Ra = wm * 64 + mi * 32 + (lane & 31);
        af[mi] = *reinterpret_cast<const bf16x8*>(&As[Ra * 64 + (kb ^ ((Ra & 7) << 3))]);
      }
      #pragma unroll
      for (int ni = 0; ni < 2; ++ni) {
        const int Rb = wn * 64 + ni * 32 + (lane & 31);
        bfr[ni] = *reinterpret_cast<const bf16x8*>(&Bs[Rb * 64 + (kb ^ ((Rb & 7) << 3))]);
      }
      #pragma unroll
      for (int mi = 0; mi < 2; ++mi)
        #pragma unroll
        for (int ni = 0; ni < 2; ++ni)
          acc[mi][ni] = __builtin_amdgcn_mfma_f32_32x32x16_bf16(af[mi], bfr[ni], acc[mi][ni], 0, 0, 0);
    }
  }

  // Epilogue: bf16 stores.  32x32 C/D: col=lane&31, row=(reg&3)+8*(reg>>2)+4*(lane>>5).
  unsigned short* __restrict__ pk = partK + (size_t)kz * ((size_t)M_DIM * OUT_DIM);
  const int hi = lane >> 5;
  const int cl = lane & 31;
  #pragma unroll
  for (int mi = 0; mi < 2; ++mi) {
    #pragma unroll
    for (int ni = 0; ni < 2; ++ni) {
      const int colb = n0 + wn * 64 + ni * 32 + cl;
      #pragma unroll
      for (int q = 0; q < 4; ++q) {
        const int rowb = wm * 64 + mi * 32 + q * 8 + hi * 4;
        #pragma unroll
        for (int j = 0; j < 4; ++j)
          pk[(size_t)(rowb + j) * OUT_DIM + colb] = f2bf(acc[mi][ni][q * 4 + j]);
      }
    }
  }
}

// ---------------------------------------------------------------------------
// K4: out = sum_kz bf2f(partK[kz]) + bias.  grid 2752, block 256.
// ---------------------------------------------------------------------------
__global__ __launch_bounds__(256) void k4_reduce(
    const unsigned short* __restrict__ partK, const float* __restrict__ bias,
    float* __restrict__ out)
{
  const size_t idx = ((size_t)blockIdx.x * 256 + threadIdx.x) * 4;
  const int col = (int)(idx % OUT_DIM);
  const size_t stride = (size_t)M_DIM * OUT_DIM;
  f32x4 s = *reinterpret_cast<const f32x4*>(&bias[col]);
  #pragma unroll
  for (int kz = 0; kz < KSPLIT; ++kz) {
    const u16x4 p = __builtin_nontemporal_load(
        reinterpret_cast<const u16x4*>(&partK[kz * stride + idx]));
    s[0] += bf2f(p[0]); s[1] += bf2f(p[1]); s[2] += bf2f(p[2]); s[3] += bf2f(p[3]);
  }
  *reinterpret_cast<f32x4*>(&out[idx]) = s;
}

// ---------------------------------------------------------------------------
extern "C" void kernel_launch(void* const* d_in, const int* in_sizes, int n_in,
                              void* d_out, int out_size, void* d_ws, size_t ws_size,
                              hipStream_t stream) {
  const float* x    = (const float*)d_in[0];
  const float* W    = (const float*)d_in[1];
  const float* lA   = (const float*)d_in[2];
  const float* lB   = (const float*)d_in[3];
  const float* lM   = (const float*)d_in[4];
  const float* bias = (const float*)d_in[5];
  float* out = (float*)d_out;

  // Workspace layout (~26.1 MB total):
  //   xs      bf16 [256*4096]        @ 0          ( 2,097,152 B)
  //   part_ss f32  [86][4096]        @ 2,097,152  ( 1,409,024 B)
  //   y       f32  [256][64]         @ 3,506,176  (    65,536 B)
  //   partK   bf16 [4][256][11008]   @ 3,571,712  (22,544,384 B)
  char* ws = (char*)d_ws;
  unsigned short* xs    = (unsigned short*)(ws);
  float* part_ss        = (float*)(ws + 2097152u);
  float* y              = (float*)(ws + 3506176u);
  unsigned short* partK = (unsigned short*)(ws + 3571712u);

  k1_norm<<<dim3(IN_DIM / 128, NBLK_O), 256, 0, stream>>>(W, lA, lB, part_ss);
  k2_xs<<<dim3(IN_DIM / 256, M_DIM / 16), 256, 0, stream>>>(x, lM, part_ss, xs, y);
  k2b_y<<<dim3(32, 4), 256, 0, stream>>>(xs, lA, y);
  k3_gemm<<<dim3(NBLK_O, KSPLIT), 512, 0, stream>>>(xs, W, lB, y, partK);
  k4_reduce<<<dim3((M_DIM * OUT_DIM) / 1024), 256, 0, stream>>>(partK, bias, out);
}

// Round 12
// 134.829 us; speedup vs baseline: 1.2253x; 1.2253x over previous
//
#include <hip/hip_runtime.h>

// LoRA-DoRA fused linear for MI355X (gfx950).
// R12 = R9 (measured best, 116.95us) + widened K1 streaming phase
// (8 cols/thread: 32B W loads, 16B Wc stores, 16B LDS reads).
// Shapes: x[256][4096] f32, W[11008][4096] f32, A[64][4096], B[11008][64],
//         M[1][4096], bias[11008]; out[256][11008] f32.
//  K1: W_c = W + 2*(B@A) -> Wc bf16; column sumsq partials -> part_ss.
//      W reads NONTEMPORAL (keep L3 for Wc/partK).
//  K2: scale = M/(sqrt(sum part_ss)+eps) fused with xs = bf16(x*scale).
//  K3: partK[kz] = xs @ Wc^T.  256x128 tile (Wc staged exactly once),
//      512 thr, 8 waves, KSPLIT=4, 32x32x16 MFMA, XOR-swizzled LDS.
//      BF16 partials (verified absmax-neutral).
//  K4: out = sum_kz bf2f(partK[kz]) + bias (nontemporal partK reads).

typedef __attribute__((ext_vector_type(8))) short bf16x8;
typedef __attribute__((ext_vector_type(4))) float f32x4;
typedef __attribute__((ext_vector_type(16))) float f32x16;
typedef __attribute__((ext_vector_type(4))) unsigned short u16x4;
typedef __attribute__((ext_vector_type(8))) unsigned short u16x8;

#define OUT_DIM 11008
#define IN_DIM  4096
#define M_DIM   256
#define KSPLIT  4
#define NBLK_O  86   // OUT_DIM / 128

static __device__ __forceinline__ unsigned short f2bf(float f) {
  union { float f; unsigned u; } v; v.f = f;
  unsigned r = (v.u + 0x7fffu + ((v.u >> 16) & 1u)) >> 16;  // RNE
  return (unsigned short)r;
}
static __device__ __forceinline__ float bf2f(unsigned short h) {
  union { unsigned u; float f; } v; v.u = ((unsigned)h) << 16;
  return v.f;
}

#define GLOAD_LDS16(gptr, lptr)                                                        \
  __builtin_amdgcn_global_load_lds(                                                    \
      (const __attribute__((address_space(1))) unsigned int*)(gptr),                   \
      (__attribute__((address_space(3))) unsigned int*)(lptr), 16, 0, 0)

// ---------------------------------------------------------------------------
// K1: combine + column sumsq partials.  grid (IN/128=32, OUT/128=86), block 256.
// ---------------------------------------------------------------------------
__global__ __launch_bounds__(256) void k1_combine(
    const float* __restrict__ W,
    const float* __restrict__ lA,   // [64][4096]
    const float* __restrict__ lB,   // [11008][64]
    unsigned short* __restrict__ Wc,
    float* __restrict__ part_ss)    // [86][4096]
{
  const int i0 = blockIdx.x * 128;
  const int o0 = blockIdx.y * 128;
  const int tid = threadIdx.x;
  const int lane = tid & 63;
  const int wid = tid >> 6;
  const int wr = wid >> 1, wc = wid & 1;

  __shared__ unsigned short smem[2][128][72];  // A^T tile / B tile; reused as L / red
  for (int idx = tid; idx < 64 * 128; idx += 256) {
    const int r = idx >> 7, c = idx & 127;
    smem[0][c][r] = f2bf(lA[r * IN_DIM + i0 + c]);
  }
  for (int idx = tid; idx < 128 * 64; idx += 256) {
    const int o = idx >> 6, r = idx & 63;
    smem[1][o][r] = f2bf(lB[(o0 + o) * 64 + r]);
  }
  __syncthreads();

  // l[128x128] = Bt(128x64) @ At(128x64)^T  via 16x16x32 bf16 MFMA
  f32x4 acc[4][4];
  #pragma unroll
  for (int a = 0; a < 4; ++a)
    #pragma unroll
    for (int b = 0; b < 4; ++b) acc[a][b] = (f32x4){0.f, 0.f, 0.f, 0.f};

  #pragma unroll
  for (int kk = 0; kk < 2; ++kk) {
    const int kofs = kk * 32 + (lane >> 4) * 8;
    bf16x8 af[4], bfr[4];
    #pragma unroll
    for (int mi = 0; mi < 4; ++mi)
      af[mi] = *reinterpret_cast<const bf16x8*>(&smem[1][wr * 64 + mi * 16 + (lane & 15)][kofs]);
    #pragma unroll
    for (int ni = 0; ni < 4; ++ni)
      bfr[ni] = *reinterpret_cast<const bf16x8*>(&smem[0][wc * 64 + ni * 16 + (lane & 15)][kofs]);
    #pragma unroll
    for (int mi = 0; mi < 4; ++mi)
      #pragma unroll
      for (int ni = 0; ni < 4; ++ni)
        acc[mi][ni] = __builtin_amdgcn_mfma_f32_16x16x32_bf16(af[mi], bfr[ni], acc[mi][ni], 0, 0, 0);
  }
  __syncthreads();

  // Spill l to LDS as bf16, row stride 136 (16B-aligned rows: 272B).
  unsigned short* L = &smem[0][0][0];
  #pragma unroll
  for (int mi = 0; mi < 4; ++mi) {
    const int ol = wr * 64 + mi * 16 + (lane >> 4) * 4;
    #pragma unroll
    for (int ni = 0; ni < 4; ++ni) {
      const int il = wc * 64 + ni * 16 + (lane & 15);
      #pragma unroll
      for (int j = 0; j < 4; ++j)
        L[(ol + j) * 136 + il] = f2bf(acc[mi][ni][j]);
    }
  }
  __syncthreads();

  // Streaming phase (R12 widened): 8 cols/thread.  Nontemporal 32B W loads,
  // 16B LDS reads, 16B Wc stores.  cg=col-group (16), r0=row (16), 8 iters.
  const int cg = (tid & 15) * 8;  // f32 column base
  const int r0 = tid >> 4;        // 0..15
  float sq[8];
  #pragma unroll
  for (int j = 0; j < 8; ++j) sq[j] = 0.f;
  #pragma unroll
  for (int it = 0; it < 8; ++it) {
    const int rr = r0 + it * 16;
    const size_t go = (size_t)(o0 + rr) * IN_DIM + i0 + cg;
    const f32x4 wa = __builtin_nontemporal_load(reinterpret_cast<const f32x4*>(&W[go]));
    const f32x4 wb = __builtin_nontemporal_load(reinterpret_cast<const f32x4*>(&W[go + 4]));
    const u16x8 lv = *reinterpret_cast<const u16x8*>(&L[rr * 136 + cg]);
    float w[8];
    w[0] = wa[0] + 2.f * bf2f(lv[0]); w[1] = wa[1] + 2.f * bf2f(lv[1]);
    w[2] = wa[2] + 2.f * bf2f(lv[2]); w[3] = wa[3] + 2.f * bf2f(lv[3]);
    w[4] = wb[0] + 2.f * bf2f(lv[4]); w[5] = wb[1] + 2.f * bf2f(lv[5]);
    w[6] = wb[2] + 2.f * bf2f(lv[6]); w[7] = wb[3] + 2.f * bf2f(lv[7]);
    u16x8 o8;
    #pragma unroll
    for (int j = 0; j < 8; ++j) { sq[j] += w[j] * w[j]; o8[j] = f2bf(w[j]); }
    *reinterpret_cast<u16x8*>(&Wc[go]) = o8;
  }
  __syncthreads();
  float* red = reinterpret_cast<float*>(L);  // [256][8] f32 = 8 KB
  #pragma unroll
  for (int j = 0; j < 8; ++j) red[tid * 8 + j] = sq[j];
  __syncthreads();
  if (tid < 128) {
    // column (i0 + tid): contributions from threads r0*16 + (tid>>3), elem tid&7.
    const int cgrp = tid >> 3, j = tid & 7;
    float s = 0.f;
    #pragma unroll
    for (int g = 0; g < 16; ++g) s += red[(g * 16 + cgrp) * 8 + j];
    part_ss[(size_t)blockIdx.y * IN_DIM + i0 + tid] = s;
  }
}

// ---------------------------------------------------------------------------
// K2: fused scale + xs.  grid (16, 16), block 256.
// ---------------------------------------------------------------------------
__global__ __launch_bounds__(256) void k2_xs(
    const float* __restrict__ x, const float* __restrict__ lM,
    const float* __restrict__ part_ss, unsigned short* __restrict__ xs)
{
  const int i = blockIdx.x * 256 + threadIdx.x;  // column
  const int b0 = blockIdx.y * 16;
  float s = 0.f;
  #pragma unroll 2
  for (int b = 0; b < NBLK_O; ++b) s += part_ss[(size_t)b * IN_DIM + i];
  const float sc = lM[i] / (sqrtf(s) + 1e-6f);
  #pragma unroll 4
  for (int r = 0; r < 16; ++r) {
    const size_t o = (size_t)(b0 + r) * IN_DIM + i;
    xs[o] = f2bf(x[o] * sc);
  }
}

// ---------------------------------------------------------------------------
// K3: partK[kz] = xs @ Wc^T over K-quarter.  grid (86, KSPLIT=4), block 512.
// 256x128 output tile (full M): each Wc element staged EXACTLY ONCE.
// 8 waves (4m x 2n), BK=64, 32x32x16 MFMA, XOR-swizzled LDS, single-buffer
// 2-barrier loop.  BF16 partial stores (verified absmax-neutral).
// ---------------------------------------------------------------------------
__global__ __launch_bounds__(512) void k3_gemm(
    const unsigned short* __restrict__ xs,  // [256][4096] bf16
    const unsigned short* __restrict__ Wc,  // [11008][4096] bf16
    unsigned short* __restrict__ partK)     // [KSPLIT][256][11008] bf16
{
  const int n0 = blockIdx.x * 128;
  const int kz = blockIdx.y;
  const int tid = threadIdx.x;
  const int lane = tid & 63;
  const int wid = tid >> 6;      // 0..7
  const int wm = wid >> 1;       // 0..3 -> m-base = wm*64
  const int wn = wid & 1;        // 0..1 -> n-base = wn*64

  __shared__ unsigned short As[256 * 64];   // 32 KB
  __shared__ unsigned short Bs[128 * 64];   // 16 KB

  f32x16 acc[2][2];
  #pragma unroll
  for (int a = 0; a < 2; ++a)
    #pragma unroll
    for (int b = 0; b < 2; ++b)
      #pragma unroll
      for (int r = 0; r < 16; ++r) acc[a][b][r] = 0.f;

  const int k0base = kz * (IN_DIM / KSPLIT);
  const int srow = tid >> 3;        // 0..63
  const int g    = tid & 7;         // 16B granule within 64-col row
  const int gc   = (g ^ (srow & 7)) * 8;  // pre-swizzled source col
  const int ldst = srow * 64 + g * 8;

  for (int ks = 0; ks < (IN_DIM / KSPLIT) / 64; ++ks) {  // 16 steps
    const int k0 = k0base + ks * 64;
    #pragma unroll
    for (int iss = 0; iss < 4; ++iss)   // xs rows srow + 64*iss  (0..255)
      GLOAD_LDS16(&xs[(size_t)(srow + 64 * iss) * IN_DIM + k0 + gc],
                  &As[iss * 64 * 64 + ldst]);
    #pragma unroll
    for (int iss = 0; iss < 2; ++iss)   // Wc rows n0 + srow + 64*iss (0..127)
      GLOAD_LDS16(&Wc[(size_t)(n0 + srow + 64 * iss) * IN_DIM + k0 + gc],
                  &Bs[iss * 64 * 64 + ldst]);
    __syncthreads();  // drains vmcnt (compiler-inserted)
    #pragma unroll
    for (int kk = 0; kk < 4; ++kk) {
      const int kb = kk * 16 + (lane >> 5) * 8;  // bf16 k-offset for this lane
      bf16x8 af[2], bfr[2];
      #pragma unroll
      for (int mi = 0; mi < 2; ++mi) {
        const int Ra = wm * 64 + mi * 32 + (lane & 31);
        af[mi] = *reinterpret_cast<const bf16x8*>(&As[Ra * 64 + (kb ^ ((Ra & 7) << 3))]);
      }
      #pragma unroll
      for (int ni = 0; ni < 2; ++ni) {
        const int Rb = wn * 64 + ni * 32 + (lane & 31);
        bfr[ni] = *reinterpret_cast<const bf16x8*>(&Bs[Rb * 64 + (kb ^ ((Rb & 7) << 3))]);
      }
      #pragma unroll
      for (int mi = 0; mi < 2; ++mi)
        #pragma unroll
        for (int ni = 0; ni < 2; ++ni)
          acc[mi][ni] = __builtin_amdgcn_mfma_f32_32x32x16_bf16(af[mi], bfr[ni], acc[mi][ni], 0, 0, 0);
    }
    __syncthreads();
  }

  // Epilogue: bf16 stores.  32x32 C/D layout: col=lane&31,
  // row=(reg&3)+8*(reg>>2)+4*(lane>>5)  [m74/m101-verified].
  unsigned short* __restrict__ pk = partK + (size_t)kz * ((size_t)M_DIM * OUT_DIM);
  const int hi = lane >> 5;
  const int cl = lane & 31;
  #pragma unroll
  for (int mi = 0; mi < 2; ++mi) {
    #pragma unroll
    for (int ni = 0; ni < 2; ++ni) {
      const int colb = n0 + wn * 64 + ni * 32 + cl;
      #pragma unroll
      for (int q = 0; q < 4; ++q) {
        const int rowb = wm * 64 + mi * 32 + q * 8 + hi * 4;
        #pragma unroll
        for (int j = 0; j < 4; ++j)
          pk[(size_t)(rowb + j) * OUT_DIM + colb] = f2bf(acc[mi][ni][q * 4 + j]);
      }
    }
  }
}

// ---------------------------------------------------------------------------
// K4: out = sum_kz bf2f(partK[kz]) + bias.  grid 2752, block 256, 4 out/thread.
// ---------------------------------------------------------------------------
__global__ __launch_bounds__(256) void k4_reduce(
    const unsigned short* __restrict__ partK, const float* __restrict__ bias,
    float* __restrict__ out)
{
  const size_t idx = ((size_t)blockIdx.x * 256 + threadIdx.x) * 4;
  const int col = (int)(idx % OUT_DIM);
  const size_t stride = (size_t)M_DIM * OUT_DIM;
  f32x4 s = *reinterpret_cast<const f32x4*>(&bias[col]);
  #pragma unroll
  for (int kz = 0; kz < KSPLIT; ++kz) {
    const u16x4 p = __builtin_nontemporal_load(
        reinterpret_cast<const u16x4*>(&partK[kz * stride + idx]));
    s[0] += bf2f(p[0]); s[1] += bf2f(p[1]); s[2] += bf2f(p[2]); s[3] += bf2f(p[3]);
  }
  *reinterpret_cast<f32x4*>(&out[idx]) = s;
}

// ---------------------------------------------------------------------------
extern "C" void kernel_launch(void* const* d_in, const int* in_sizes, int n_in,
                              void* d_out, int out_size, void* d_ws, size_t ws_size,
                              hipStream_t stream) {
  const float* x    = (const float*)d_in[0];
  const float* W    = (const float*)d_in[1];
  const float* lA   = (const float*)d_in[2];
  const float* lB   = (const float*)d_in[3];
  const float* lM   = (const float*)d_in[4];
  const float* bias = (const float*)d_in[5];
  float* out = (float*)d_out;

  // Workspace layout (~116.3 MB total):
  //   Wc      bf16 [11008*4096]      @ 0          (90,177,536 B)
  //   xs      bf16 [256*4096]        @ 90,177,536 ( 2,097,152 B)
  //   part_ss f32  [86][4096]        @ 92,291,072 ( 1,409,024 B)
  //   partK   bf16 [4][256][11008]   @ 93,700,096 (22,544,384 B)
  char* ws = (char*)d_ws;
  unsigned short* Wc    = (unsigned short*)(ws);
  unsigned short* xs    = (unsigned short*)(ws + 90177536u);
  float* part_ss        = (float*)(ws + 92291072u);
  unsigned short* partK = (unsigned short*)(ws + 93700096u);

  k1_combine<<<dim3(IN_DIM / 128, NBLK_O), 256, 0, stream>>>(W, lA, lB, Wc, part_ss);
  k2_xs<<<dim3(IN_DIM / 256, M_DIM / 16), 256, 0, stream>>>(x, lM, part_ss, xs);
  k3_gemm<<<dim3(NBLK_O, KSPLIT), 512, 0, stream>>>(xs, Wc, partK);
  k4_reduce<<<dim3((M_DIM * OUT_DIM) / 1024), 256, 0, stream>>>(partK, bias, out);
}

// Round 13
// 116.864 us; speedup vs baseline: 1.4136x; 1.1537x over previous
//
#include <hip/hip_runtime.h>

// LoRA-DoRA fused linear for MI355X (gfx950).
// R13 = R9 verbatim (measured best: 116.95us).  R10-R12 experiments (no-Wc
// restructure, K1 stream widening) all regressed; this re-establishes the
// empirical optimum of the Wc-materialized 4-kernel structure.
// Shapes: x[256][4096] f32, W[11008][4096] f32, A[64][4096], B[11008][64],
//         M[1][4096], bias[11008]; out[256][11008] f32.
//  K1: W_c = W + 2*(B@A) -> Wc bf16; column sumsq partials -> part_ss.
//      W reads NONTEMPORAL (keep L3 for Wc/partK); 32-lane-contiguous f32x4
//      loads (per-instruction coalescing — R12's wider variant broke this).
//  K2: scale = M/(sqrt(sum part_ss)+eps) fused with xs = bf16(x*scale).
//  K3: partK[kz] = xs @ Wc^T.  256x128 tile (Wc staged exactly once),
//      512 thr, 8 waves, KSPLIT=4 (344 blocks, measured best vs 2/8),
//      32x32x16 MFMA, XOR-swizzled LDS, single-buffer 2-barrier loop.
//      BF16 partials (verified absmax-neutral).
//  K4: out = sum_kz bf2f(partK[kz]) + bias (nontemporal partK reads).

typedef __attribute__((ext_vector_type(8))) short bf16x8;
typedef __attribute__((ext_vector_type(4))) float f32x4;
typedef __attribute__((ext_vector_type(16))) float f32x16;
typedef __attribute__((ext_vector_type(4))) unsigned short u16x4;

#define OUT_DIM 11008
#define IN_DIM  4096
#define M_DIM   256
#define KSPLIT  4
#define NBLK_O  86   // OUT_DIM / 128

static __device__ __forceinline__ unsigned short f2bf(float f) {
  union { float f; unsigned u; } v; v.f = f;
  unsigned r = (v.u + 0x7fffu + ((v.u >> 16) & 1u)) >> 16;  // RNE
  return (unsigned short)r;
}
static __device__ __forceinline__ float bf2f(unsigned short h) {
  union { unsigned u; float f; } v; v.u = ((unsigned)h) << 16;
  return v.f;
}

#define GLOAD_LDS16(gptr, lptr)                                                        \
  __builtin_amdgcn_global_load_lds(                                                    \
      (const __attribute__((address_space(1))) unsigned int*)(gptr),                   \
      (__attribute__((address_space(3))) unsigned int*)(lptr), 16, 0, 0)

// ---------------------------------------------------------------------------
// K1: combine + column sumsq partials.  grid (IN/128=32, OUT/128=86), block 256.
// ---------------------------------------------------------------------------
__global__ __launch_bounds__(256) void k1_combine(
    const float* __restrict__ W,
    const float* __restrict__ lA,   // [64][4096]
    const float* __restrict__ lB,   // [11008][64]
    unsigned short* __restrict__ Wc,
    float* __restrict__ part_ss)    // [86][4096]
{
  const int i0 = blockIdx.x * 128;
  const int o0 = blockIdx.y * 128;
  const int tid = threadIdx.x;
  const int lane = tid & 63;
  const int wid = tid >> 6;
  const int wr = wid >> 1, wc = wid & 1;

  __shared__ unsigned short smem[2][128][72];  // [0]=A^T tile, [1]=B tile; reused as L / red
  // Stage A^T: At[c][r] = A[r][i0+c]  (bf16)
  for (int idx = tid; idx < 64 * 128; idx += 256) {
    const int r = idx >> 7, c = idx & 127;
    smem[0][c][r] = f2bf(lA[r * IN_DIM + i0 + c]);
  }
  // Stage B: Bt[o][r] = lB[o0+o][r]
  for (int idx = tid; idx < 128 * 64; idx += 256) {
    const int o = idx >> 6, r = idx & 63;
    smem[1][o][r] = f2bf(lB[(o0 + o) * 64 + r]);
  }
  __syncthreads();

  // l[128x128] = Bt(128x64) @ At(128x64)^T  via 16x16x32 bf16 MFMA
  f32x4 acc[4][4];
  #pragma unroll
  for (int a = 0; a < 4; ++a)
    #pragma unroll
    for (int b = 0; b < 4; ++b) acc[a][b] = (f32x4){0.f, 0.f, 0.f, 0.f};

  #pragma unroll
  for (int kk = 0; kk < 2; ++kk) {
    const int kofs = kk * 32 + (lane >> 4) * 8;
    bf16x8 af[4], bfr[4];
    #pragma unroll
    for (int mi = 0; mi < 4; ++mi)
      af[mi] = *reinterpret_cast<const bf16x8*>(&smem[1][wr * 64 + mi * 16 + (lane & 15)][kofs]);
    #pragma unroll
    for (int ni = 0; ni < 4; ++ni)
      bfr[ni] = *reinterpret_cast<const bf16x8*>(&smem[0][wc * 64 + ni * 16 + (lane & 15)][kofs]);
    #pragma unroll
    for (int mi = 0; mi < 4; ++mi)
      #pragma unroll
      for (int ni = 0; ni < 4; ++ni)
        acc[mi][ni] = __builtin_amdgcn_mfma_f32_16x16x32_bf16(af[mi], bfr[ni], acc[mi][ni], 0, 0, 0);
  }
  __syncthreads();

  // Spill l to LDS as bf16, row stride 136 (bank-friendly), overwriting At/Bt.
  unsigned short* L = &smem[0][0][0];
  #pragma unroll
  for (int mi = 0; mi < 4; ++mi) {
    const int ol = wr * 64 + mi * 16 + (lane >> 4) * 4;
    #pragma unroll
    for (int ni = 0; ni < 4; ++ni) {
      const int il = wc * 64 + ni * 16 + (lane & 15);
      #pragma unroll
      for (int j = 0; j < 4; ++j)
        L[(ol + j) * 136 + il] = f2bf(acc[mi][ni][j]);
    }
  }
  __syncthreads();

  // Combine phase: nontemporal f32x4 reads of W (streamed once — keep L3
  // for Wc/partK), ds_read_b64 of L, bf16x4 writes of W_c, sumsq accum.
  const int c4 = (tid & 31) * 4;  // column chunk (fixed per thread)
  const int r0 = tid >> 5;        // 0..7
  float sq0 = 0.f, sq1 = 0.f, sq2 = 0.f, sq3 = 0.f;
  #pragma unroll
  for (int it = 0; it < 16; ++it) {
    const int rr = r0 + it * 8;
    const size_t go = (size_t)(o0 + rr) * IN_DIM + i0 + c4;
    const f32x4 w = __builtin_nontemporal_load(reinterpret_cast<const f32x4*>(&W[go]));
    const u16x4 lv = *reinterpret_cast<const u16x4*>(&L[rr * 136 + c4]);  // 8B-aligned
    const float w0 = w[0] + 2.f * bf2f(lv[0]);
    const float w1 = w[1] + 2.f * bf2f(lv[1]);
    const float w2 = w[2] + 2.f * bf2f(lv[2]);
    const float w3 = w[3] + 2.f * bf2f(lv[3]);
    sq0 += w0 * w0; sq1 += w1 * w1; sq2 += w2 * w2; sq3 += w3 * w3;
    u16x4 o4 = {f2bf(w0), f2bf(w1), f2bf(w2), f2bf(w3)};
    *reinterpret_cast<u16x4*>(&Wc[go]) = o4;
  }
  __syncthreads();
  float* red = reinterpret_cast<float*>(L);  // 256*4 floats
  red[((r0 << 5) | (tid & 31)) * 4 + 0] = sq0;
  red[((r0 << 5) | (tid & 31)) * 4 + 1] = sq1;
  red[((r0 << 5) | (tid & 31)) * 4 + 2] = sq2;
  red[((r0 << 5) | (tid & 31)) * 4 + 3] = sq3;
  __syncthreads();
  if (tid < 128) {
    const int cc = tid >> 2, k = tid & 3;
    float s = 0.f;
    #pragma unroll
    for (int g = 0; g < 8; ++g) s += red[(((g << 5) | cc) << 2) + k];
    part_ss[(size_t)blockIdx.y * IN_DIM + i0 + tid] = s;
  }
}

// ---------------------------------------------------------------------------
// K2: fused scale + xs.  grid (16, 16), block 256.
// ---------------------------------------------------------------------------
__global__ __launch_bounds__(256) void k2_xs(
    const float* __restrict__ x, const float* __restrict__ lM,
    const float* __restrict__ part_ss, unsigned short* __restrict__ xs)
{
  const int i = blockIdx.x * 256 + threadIdx.x;  // column
  const int b0 = blockIdx.y * 16;
  float s = 0.f;
  #pragma unroll 2
  for (int b = 0; b < NBLK_O; ++b) s += part_ss[(size_t)b * IN_DIM + i];
  const float sc = lM[i] / (sqrtf(s) + 1e-6f);
  #pragma unroll 4
  for (int r = 0; r < 16; ++r) {
    const size_t o = (size_t)(b0 + r) * IN_DIM + i;
    xs[o] = f2bf(x[o] * sc);
  }
}

// ---------------------------------------------------------------------------
// K3: partK[kz] = xs @ Wc^T over K-quarter.  grid (86, KSPLIT=4), block 512.
// 256x128 output tile (full M): each Wc element staged EXACTLY ONCE.
// 8 waves (4m x 2n), BK=64, 32x32x16 MFMA, XOR-swizzled LDS, single-buffer
// 2-barrier loop.  BF16 partial stores (verified absmax-neutral).
// ---------------------------------------------------------------------------
__global__ __launch_bounds__(512) void k3_gemm(
    const unsigned short* __restrict__ xs,  // [256][4096] bf16
    const unsigned short* __restrict__ Wc,  // [11008][4096] bf16
    unsigned short* __restrict__ partK)     // [KSPLIT][256][11008] bf16
{
  const int n0 = blockIdx.x * 128;
  const int kz = blockIdx.y;
  const int tid = threadIdx.x;
  const int lane = tid & 63;
  const int wid = tid >> 6;      // 0..7
  const int wm = wid >> 1;       // 0..3 -> m-base = wm*64
  const int wn = wid & 1;        // 0..1 -> n-base = wn*64

  __shared__ unsigned short As[256 * 64];   // 32 KB
  __shared__ unsigned short Bs[128 * 64];   // 16 KB

  f32x16 acc[2][2];
  #pragma unroll
  for (int a = 0; a < 2; ++a)
    #pragma unroll
    for (int b = 0; b < 2; ++b)
      #pragma unroll
      for (int r = 0; r < 16; ++r) acc[a][b][r] = 0.f;

  const int k0base = kz * (IN_DIM / KSPLIT);
  const int srow = tid >> 3;        // 0..63
  const int g    = tid & 7;         // 16B granule within 64-col row
  const int gc   = (g ^ (srow & 7)) * 8;  // pre-swizzled source col (row&7 == srow&7)
  const int ldst = srow * 64 + g * 8;

  for (int ks = 0; ks < (IN_DIM / KSPLIT) / 64; ++ks) {  // 16 steps
    const int k0 = k0base + ks * 64;
    #pragma unroll
    for (int iss = 0; iss < 4; ++iss)   // xs rows srow + 64*iss  (0..255)
      GLOAD_LDS16(&xs[(size_t)(srow + 64 * iss) * IN_DIM + k0 + gc],
                  &As[iss * 64 * 64 + ldst]);
    #pragma unroll
    for (int iss = 0; iss < 2; ++iss)   // Wc rows n0 + srow + 64*iss (0..127)
      GLOAD_LDS16(&Wc[(size_t)(n0 + srow + 64 * iss) * IN_DIM + k0 + gc],
                  &Bs[iss * 64 * 64 + ldst]);
    __syncthreads();  // drains vmcnt (compiler-inserted)
    #pragma unroll
    for (int kk = 0; kk < 4; ++kk) {
      const int kb = kk * 16 + (lane >> 5) * 8;  // bf16 k-offset for this lane
      bf16x8 af[2], bfr[2];
      #pragma unroll
      for (int mi = 0; mi < 2; ++mi) {
        const int Ra = wm * 64 + mi * 32 + (lane & 31);
        af[mi] = *reinterpret_cast<const bf16x8*>(&As[Ra * 64 + (kb ^ ((Ra & 7) << 3))]);
      }
      #pragma unroll
      for (int ni = 0; ni < 2; ++ni) {
        const int Rb = wn * 64 + ni * 32 + (lane & 31);
        bfr[ni] = *reinterpret_cast<const bf16x8*>(&Bs[Rb * 64 + (kb ^ ((Rb & 7) << 3))]);
      }
      #pragma unroll
      for (int mi = 0; mi < 2; ++mi)
        #pragma unroll
        for (int ni = 0; ni < 2; ++ni)
          acc[mi][ni] = __builtin_amdgcn_mfma_f32_32x32x16_bf16(af[mi], bfr[ni], acc[mi][ni], 0, 0, 0);
    }
    __syncthreads();
  }

  // Epilogue: bf16 stores.  32x32 C/D layout: col=lane&31,
  // row=(reg&3)+8*(reg>>2)+4*(lane>>5)  [m74/m101-verified].
  unsigned short* __restrict__ pk = partK + (size_t)kz * ((size_t)M_DIM * OUT_DIM);
  const int hi = lane >> 5;
  const int cl = lane & 31;
  #pragma unroll
  for (int mi = 0; mi < 2; ++mi) {
    #pragma unroll
    for (int ni = 0; ni < 2; ++ni) {
      const int colb = n0 + wn * 64 + ni * 32 + cl;
      #pragma unroll
      for (int q = 0; q < 4; ++q) {
        const int rowb = wm * 64 + mi * 32 + q * 8 + hi * 4;
        #pragma unroll
        for (int j = 0; j < 4; ++j)
          pk[(size_t)(rowb + j) * OUT_DIM + colb] = f2bf(acc[mi][ni][q * 4 + j]);
      }
    }
  }
}

// ---------------------------------------------------------------------------
// K4: out = sum_kz bf2f(partK[kz]) + bias.  grid 2752, block 256, 4 out/thread.
// partK reads nontemporal (consumed once, never re-read).
// ---------------------------------------------------------------------------
__global__ __launch_bounds__(256) void k4_reduce(
    const unsigned short* __restrict__ partK, const float* __restrict__ bias,
    float* __restrict__ out)
{
  const size_t idx = ((size_t)blockIdx.x * 256 + threadIdx.x) * 4;
  const int col = (int)(idx % OUT_DIM);
  const size_t stride = (size_t)M_DIM * OUT_DIM;
  f32x4 s = *reinterpret_cast<const f32x4*>(&bias[col]);
  #pragma unroll
  for (int kz = 0; kz < KSPLIT; ++kz) {
    const u16x4 p = __builtin_nontemporal_load(
        reinterpret_cast<const u16x4*>(&partK[kz * stride + idx]));
    s[0] += bf2f(p[0]); s[1] += bf2f(p[1]); s[2] += bf2f(p[2]); s[3] += bf2f(p[3]);
  }
  *reinterpret_cast<f32x4*>(&out[idx]) = s;
}

// ---------------------------------------------------------------------------
extern "C" void kernel_launch(void* const* d_in, const int* in_sizes, int n_in,
                              void* d_out, int out_size, void* d_ws, size_t ws_size,
                              hipStream_t stream) {
  const float* x    = (const float*)d_in[0];
  const float* W    = (const float*)d_in[1];
  const float* lA   = (const float*)d_in[2];
  const float* lB   = (const float*)d_in[3];
  const float* lM   = (const float*)d_in[4];
  const float* bias = (const float*)d_in[5];
  float* out = (float*)d_out;

  // Workspace layout (~116.3 MB total):
  //   Wc      bf16 [11008*4096]      @ 0          (90,177,536 B)
  //   xs      bf16 [256*4096]        @ 90,177,536 ( 2,097,152 B)
  //   part_ss f32  [86][4096]        @ 92,291,072 ( 1,409,024 B)
  //   partK   bf16 [4][256][11008]   @ 93,700,096 (22,544,384 B)
  char* ws = (char*)d_ws;
  unsigned short* Wc    = (unsigned short*)(ws);
  unsigned short* xs    = (unsigned short*)(ws + 90177536u);
  float* part_ss        = (float*)(ws + 92291072u);
  unsigned short* partK = (unsigned short*)(ws + 93700096u);

  k1_combine<<<dim3(IN_DIM / 128, NBLK_O), 256, 0, stream>>>(W, lA, lB, Wc, part_ss);
  k2_xs<<<dim3(IN_DIM / 256, M_DIM / 16), 256, 0, stream>>>(x, lM, part_ss, xs);
  k3_gemm<<<dim3(NBLK_O, KSPLIT), 512, 0, stream>>>(xs, Wc, partK);
  k4_reduce<<<dim3((M_DIM * OUT_DIM) / 1024), 256, 0, stream>>>(partK, bias, out);
}